// Round 8
// baseline (116.324 us; speedup 1.0000x reference)
//
#include <hip/hip_runtime.h>
#include <hip/hip_bf16.h>

typedef __attribute__((ext_vector_type(4)))  float f32x4;
typedef __attribute__((ext_vector_type(16))) float f32x16;
typedef __attribute__((ext_vector_type(8)))  short bf16x8;

#define LOG2E 1.44269504088896340736f

// native v_exp_f32 (1 instr, ~1 ulp); plain exp2f lowers to precise OCML (~30 cyc).
#if __has_builtin(__builtin_amdgcn_exp2f)
static __device__ __forceinline__ float exp2_native(float x) {
  return __builtin_amdgcn_exp2f(x);
}
#else
extern "C" __device__ float __ocml_native_exp2_f32(float);
static __device__ __forceinline__ float exp2_native(float x) {
  return __ocml_native_exp2_f32(x);
}
#endif

// bf16 truncation pack: low ushort <- a, high ushort <- b (1x v_perm_b32).
static __device__ __forceinline__ unsigned int pack_trunc_f(float a, float b) {
  return __builtin_amdgcn_perm(__float_as_uint(b), __float_as_uint(a), 0x07060302);
}

// async global->LDS, 16B/lane: LDS dest = wave-uniform base + lane*16 (HW adds)
typedef const __attribute__((address_space(1))) unsigned int gu32;
typedef __attribute__((address_space(3))) unsigned int lu32;
static __device__ __forceinline__ void gload_lds16(const void* g, void* l) {
  __builtin_amdgcn_global_load_lds((gu32*)g, (lu32*)l, 16, 0, 0);
}

// ---------------------------------------------------------------------------
// proj: y = x(32768x64) * K^T(64x80) via MFMA 16x16x32. Block=256thr/4 waves.
// g-columns pre-scaled by log2(e) so attn can use native exp2 directly.
// h stored per 128-key tile as [c][136] bf16 (8-slot pad, garbage) with keys
// at PERMUTED position kpos = bitswap2<->3(key&127): attn's S^T C-layout ==
// PV A-layout with contiguous B-frags. (Stride 136 = 68 words == 4 mod 32:
// 8-lane b128 phases hit distinct banks -> 0 conflicts, measured R4/R5.)
// XCD-batch pinning: block id -> blk = (id&7)*64 + id>>3, so batch
// bt = blk>>6 = id&7 == XCD (round-robin dispatch): each batch's
// h_p/f_b/g_b writes land (and stay) in that XCD's L2 for attn to re-read.
// ---------------------------------------------------------------------------
__global__ __launch_bounds__(256) void proj_kernel(
    const float* __restrict__ x, const float* __restrict__ kf,
    const float* __restrict__ kg, const float* __restrict__ kh,
    unsigned short* __restrict__ f_b, unsigned short* __restrict__ g_b,
    unsigned short* __restrict__ h_p)
{
  __shared__ unsigned short Kt[80*72];
  const int t = threadIdx.x;
  const int idb = blockIdx.x;
  const int blk = (idb & 7)*64 + (idb >> 3);   // batch = blk>>6 = idb&7 = XCD

  #pragma unroll
  for (int r = 0; r < 20; ++r) {
    int idx = r*256 + t;                 // 5120 = 80x64
    int o = idx >> 6, c = idx & 63;
    float v = (o < 8) ? kf[c*8 + o]
            : (o < 16) ? kg[c*8 + (o-8)] * LOG2E
            : kh[c*64 + (o-16)];
    Kt[o*72 + c] = (unsigned short)(__float_as_uint(v) >> 16);
  }
  __syncthreads();

  const int w = t >> 6, lane = t & 63, l15 = lane & 15, quad = lane >> 4;
  const int Rbase = blk*64 + w*16;
  const int R = Rbase + l15;

  bf16x8 af[2];
  #pragma unroll
  for (int kk = 0; kk < 2; ++kk) {
    const float* xp = x + (long)R*64 + kk*32 + quad*8;
    float4 v0 = *(const float4*)xp;
    float4 v1 = *(const float4*)(xp + 4);
    union { unsigned int u[4]; bf16x8 v; } p;
    p.u[0] = pack_trunc_f(v0.x, v0.y);
    p.u[1] = pack_trunc_f(v0.z, v0.w);
    p.u[2] = pack_trunc_f(v1.x, v1.y);
    p.u[3] = pack_trunc_f(v1.z, v1.w);
    af[kk] = p.v;
  }

  f32x4 acc[5];
  #pragma unroll
  for (int nt = 0; nt < 5; ++nt) { f32x4 z = {}; acc[nt] = z; }

  #pragma unroll
  for (int nt = 0; nt < 5; ++nt)
    #pragma unroll
    for (int kk = 0; kk < 2; ++kk) {
      bf16x8 bfv = *(const bf16x8*)&Kt[(nt*16 + l15)*72 + kk*32 + quad*8];
      acc[nt] = __builtin_amdgcn_mfma_f32_16x16x32_bf16(af[kk], bfv, acc[nt], 0, 0, 0);
    }

  const int bt = Rbase >> 12;
  const int kt = (Rbase >> 7) & 31;
  const int base = ((blk & 1) << 6) + (w << 4);
  // permuted store position: swap bits 2<->3 of (base + 4*quad + rr)
  const int pi = base + ((quad & 1) << 3) + (((quad >> 1) & 1) << 2);

  #pragma unroll
  for (int rr = 0; rr < 4; ++rr) {
    const int nq = (Rbase + quad*4 + rr) & 4095;
    unsigned short v = (unsigned short)(__float_as_uint(acc[0][rr]) >> 16);
    if (l15 < 8) f_b[((long)bt*4096 + nq)*8 + l15] = v;
    else         g_b[((long)bt*4096 + nq)*8 + (l15 - 8)] = v;
  }
  #pragma unroll
  for (int nt = 1; nt < 5; ++nt) {
    const int c = (nt - 1)*16 + l15;
    uint2 v;
    v.x = pack_trunc_f(acc[nt][0], acc[nt][1]);
    v.y = pack_trunc_f(acc[nt][2], acc[nt][3]);
    *(uint2*)(h_p + ((long)(bt*32 + kt)*64 + c)*136 + pi) = v;
  }
}

// ---------------------------------------------------------------------------
// attn: full-K flash attention, 64 queries/block, 512 thr = 8 waves, TWO
// q-groups PER WAVE (R0 inner structure): wave w = subtile w of a 256-key
// tile-PAIR (tl = w>>2, mt = w&3); its 1 afv + 4 bh LDS reads feed BOTH
// q-groups -> per-output LDS reads halve (2560 -> 1280 b128/CU vs R7), and
// the two independent sc->exp2->pack->PV chains interleave to fill each
// other's latency stalls (the mechanism occupancy -- a measured-null lever
// across 1-4 waves/SIMD -- failed to provide; ~96 acc VGPRs pin this at
// 2 waves/SIMD, which R0/R1 A/B showed performs as well as 4).
// Pair double-buffer: 2 x 38912 = 77824 B dynamic LDS, 16 barriers.
// Grid 512 blocks, XCD-pinned (b = id&7): per-XCD hot set 622 KB << 4 MiB
// L2, so the 318 MB re-stage stream is local-L2 (R6-measured regime).
// l accumulated via ones-column PV MFMA (col 0). Combine: ks-reduction over
// 8 waves per q-group via LDS, stride 49 words (17*l mod 32 bijection ->
// conflict-free, measured 0 since R5), 3 rounds of <=6 sub-slots (75,260 B
// <= 77,824); wave 0 normalizes and writes out = gamma*o/l + x.
// No fences, no extra dispatch (R2 lesson).
// ---------------------------------------------------------------------------
__global__ __launch_bounds__(512, 2) void attn_kernel(
    const unsigned short* __restrict__ f_b, const unsigned short* __restrict__ g_b,
    const unsigned short* __restrict__ h_p,
    const float* __restrict__ x, const float* __restrict__ gamma_p,
    float* __restrict__ out)
{
  extern __shared__ char smem[];   // 77824 B: pair buf bi at bi*38912; combine reuses

  const int t = threadIdx.x;
  const int w = t >> 6, lane = t & 63, l31 = lane & 31, a = lane >> 5;
  const int tl = w >> 2, mt = w & 3;     // tile-in-pair, subtile-in-tile
  const int id = blockIdx.x;
  const int b = id & 7, qb = id >> 3;    // batch = XCD (round-robin)
  const int q0 = qb*64;

  // g B-frags, one per q-group: n = q = l31, k = a*8+j ; real only at a=0
  bf16x8 gf[2];
  #pragma unroll
  for (int qg = 0; qg < 2; ++qg) {
    bf16x8 gv = *(const bf16x8*)(g_b + ((long)b*4096 + q0 + qg*32 + l31)*8);
    bf16x8 z = {};
    gf[qg] = (a == 0) ? gv : z;
  }
  // ones B-frag (col 0 only): accumulates l = sum_k P via the PV MFMA
  bf16x8 bhl;
  {
    union { unsigned short s[8]; bf16x8 v; } o8;
    #pragma unroll
    for (int j = 0; j < 8; ++j) o8.s[j] = 0x3F80;   // bf16 1.0
    bf16x8 z = {};
    bhl = (l31 == 0) ? o8.v : z;
  }

  f32x16 oacc[2][2], ol[2];
  { f32x16 z = {};
    oacc[0][0] = z; oacc[0][1] = z; oacc[1][0] = z; oacc[1][1] = z;
    ol[0] = z; ol[1] = z; }

  const char* hp_b = (const char*)h_p + (long)b*32*17408;
  const char* fb_b = (const char*)f_b + (long)b*4096*16;

  // stage tile-PAIR {2*tp, 2*tp+1} into buffer bi: 38 chunks of 1024 B,
  // wave w takes chunks c = i*8 + w (counts 5,5,5,5,5,5,4,4).
  // Sub-layout: two consecutive 19456-B blocks (17408 h + 2048 f).
  auto stage = [&](int bi, int tp) {
    char* dst = smem + bi*38912;
    #pragma unroll
    for (int i = 0; i < 5; ++i) {
      const int c = i*8 + w;
      if (c < 38) {
        const int off = c*1024;
        const int sub = (off >= 19456);
        const int kt = tp*2 + sub;
        const int within = off - sub*19456;
        const char* src = (within < 17408)
            ? (hp_b + (long)kt*17408 + within)
            : (fb_b + (long)kt*2048 + (within - 17408));
        gload_lds16(src + lane*16, dst + off);
      }
    }
  };

  stage(0, 0);

  for (int tp = 0; tp < 16; ++tp) {
    __syncthreads();                     // drains pair-tp loads; protects reuse
    if (tp < 15) stage((tp + 1) & 1, tp + 1);

    const char* bufb = smem + (tp & 1)*38912;
    const unsigned short* hts = (const unsigned short*)(bufb + tl*19456);
    const unsigned short* fts = hts + 8704;   // f block at byte 17408

    // this wave's subtile: keys mt*32.. (storage order) of tile tl
    bf16x8 afv = *(const bf16x8*)&fts[(mt*32 + l31)*8];
    f32x16 zz = {};
    f32x16 sc0 = __builtin_amdgcn_mfma_f32_32x32x16_bf16(afv, gf[0], zz, 0, 0, 0);
    f32x16 sc1 = __builtin_amdgcn_mfma_f32_32x32x16_bf16(afv, gf[1], zz, 0, 0, 0);

    #pragma unroll
    for (int half = 0; half < 2; ++half) {
      const int s = mt*2 + half;         // PV K-step: contraction k in [16s,16s+16)
      bf16x8 bh0 = *(const bf16x8*)&hts[(l31)*136      + s*16 + a*8];
      bf16x8 bh1 = *(const bf16x8*)&hts[(32 + l31)*136 + s*16 + a*8];
      union { unsigned int u[4]; bf16x8 v; } ap0, ap1;
      #pragma unroll
      for (int j = 0; j < 4; ++j) {
        float e0a = exp2_native(sc0[half*8 + 2*j]);    // g pre-scaled by log2e
        float e0b = exp2_native(sc0[half*8 + 2*j + 1]);
        float e1a = exp2_native(sc1[half*8 + 2*j]);
        float e1b = exp2_native(sc1[half*8 + 2*j + 1]);
        ap0.u[j] = pack_trunc_f(e0a, e0b);
        ap1.u[j] = pack_trunc_f(e1a, e1b);
      }
      oacc[0][0] = __builtin_amdgcn_mfma_f32_32x32x16_bf16(ap0.v, bh0, oacc[0][0], 0, 0, 0);
      oacc[0][1] = __builtin_amdgcn_mfma_f32_32x32x16_bf16(ap0.v, bh1, oacc[0][1], 0, 0, 0);
      ol[0]      = __builtin_amdgcn_mfma_f32_32x32x16_bf16(ap0.v, bhl, ol[0],      0, 0, 0);
      oacc[1][0] = __builtin_amdgcn_mfma_f32_32x32x16_bf16(ap1.v, bh0, oacc[1][0], 0, 0, 0);
      oacc[1][1] = __builtin_amdgcn_mfma_f32_32x32x16_bf16(ap1.v, bh1, oacc[1][1], 0, 0, 0);
      ol[1]      = __builtin_amdgcn_mfma_f32_32x32x16_bf16(ap1.v, bhl, ol[1],      0, 0, 0);
    }
  }

  // ---- 8-way wave-combine per q-group (LDS, stride 49 words, 3 rounds) ----
  __syncthreads();                       // all compute done; stream reusable
  float* cb = (float*)smem;
  #pragma unroll
  for (int rnd = 0; rnd < 3; ++rnd) {
    const int lo = rnd*3 + 1;            // source waves {1,2,3},{4,5,6},{7}
    if (w >= lo && w < lo + 3) {
      #pragma unroll
      for (int qg = 0; qg < 2; ++qg) {
        float* d = cb + (((w - lo)*2 + qg)*64 + lane)*49;
        #pragma unroll
        for (int r = 0; r < 16; ++r) {
          d[r] = oacc[qg][0][r]; d[16 + r] = oacc[qg][1][r]; d[32 + r] = ol[qg][r];
        }
      }
    }
    __syncthreads();
    if (w == 0) {
      const int nsl = (rnd == 2) ? 1 : 3;
      for (int sl = 0; sl < nsl; ++sl) {
        #pragma unroll
        for (int qg = 0; qg < 2; ++qg) {
          const float* sp = cb + ((sl*2 + qg)*64 + lane)*49;
          #pragma unroll
          for (int r = 0; r < 16; ++r) {
            oacc[qg][0][r] += sp[r];
            oacc[qg][1][r] += sp[16 + r];
            ol[qg][r]      += sp[32 + r];
          }
        }
      }
    }
    __syncthreads();
  }

  if (w == 0) {
    const float gamma = gamma_p[0];
    #pragma unroll
    for (int qg = 0; qg < 2; ++qg) {
      const float* xb = x + ((long)b*4096 + q0 + qg*32)*64;
      float* ob = out + ((long)b*4096 + q0 + qg*32)*64;
      #pragma unroll
      for (int r = 0; r < 16; ++r) {
        const int q = (r & 3) + 8*(r >> 2) + 4*a;   // C row for this acc reg
        // l for row q lives in col-0 lane of this 32-half (lane 0 / lane 32)
        const float lq = __shfl(ol[qg][r], lane & 32);
        const float s = gamma / lq;
        #pragma unroll
        for (int nt = 0; nt < 2; ++nt) {
          const long idx = (long)q*64 + nt*32 + l31; // col c = nt*32+l31
          ob[idx] = fmaf(s, oacc[qg][nt][r], xb[idx]);
        }
      }
    }
  }
}

extern "C" void kernel_launch(void* const* d_in, const int* in_sizes, int n_in,
                              void* d_out, int out_size, void* d_ws, size_t ws_size,
                              hipStream_t stream) {
  const float* x  = (const float*)d_in[0];
  const float* kf = (const float*)d_in[1];
  const float* kg = (const float*)d_in[2];
  const float* kh = (const float*)d_in[3];
  const float* gamma = (const float*)d_in[4];
  float* out = (float*)d_out;

  char* ws = (char*)d_ws;
  unsigned short* h_p = (unsigned short*)ws;                  // 8*32*64*136*2 = 4,456,448
  unsigned short* f_b = (unsigned short*)(ws + 4456448);      // 524,288
  unsigned short* g_b = (unsigned short*)(ws + 4980736);      // 524,288

  proj_kernel<<<512, 256, 0, stream>>>(x, kf, kg, kh, f_b, g_b, h_p);
  attn_kernel<<<512, 512, 77824, stream>>>(f_b, g_b, h_p, x, gamma, out);
}